// Round 6
// baseline (740.873 us; speedup 1.0000x reference)
//
#include <hip/hip_runtime.h>
#include <cfloat>

// VectorQuantizer: z_in [16,256,64,64] fp32, emb [1024,256] fp32
#define HW      4096
#define DIM     256
#define KCODES  1024
#define NVEC    65536
#define OUTHALF 16777216

// score-kernel tiling
#define TN   128   // vectors per block
#define TK   128   // codes per k-tile
#define DC   32    // d-chunk staged in LDS
#define ESTR 132   // padded e-tile row stride (16B-aligned rows: 132*4=528)

// forces x to be materialized (rounded) — prevents mul+add fma contraction
#define FBAR(x) asm volatile("" : "+v"(x))

struct StageMem {
  float z[DC][TN];    // 16 KB
  float e[DC][ESTR];  // 16.5 KB, e[d][code]
};
struct MergeMem {
  float m1[16][TN];
  int   i1[16][TN];
};
union __align__(16) SmemB {
  StageMem s;
  MergeMem m;
};

// numpy pairwise_sum replication for sum of 128 squares (stride in elements):
// r[0..7] accumulate stride-8, combine ((r0+r1)+(r2+r3)) + ((r4+r5)+(r6+r7)).
// Squares are individually rounded (numpy materializes x**2 first) — FBAR blocks fma.
__device__ __forceinline__ float pairwise_sq_128(const float* __restrict__ p, long stride) {
  float r[8];
  #pragma unroll
  for (int j = 0; j < 8; ++j) {
    float v = p[(size_t)j * stride];
    float s = v * v; FBAR(s);
    r[j] = s;
  }
  for (int i = 8; i < 128; i += 8) {
    #pragma unroll
    for (int j = 0; j < 8; ++j) {
      float v = p[(size_t)(i + j) * stride];
      float s = v * v; FBAR(s);
      r[j] += s;                       // plain fp32 add (s already rounded)
    }
  }
  return ((r[0] + r[1]) + (r[2] + r[3])) + ((r[4] + r[5]) + (r[6] + r[7]));
}

// ---------------- kernel A: Z_n = fl32 sum(z_n^2), numpy tree (two 128-halves) ----------------
__global__ __launch_bounds__(256) void zsq_kernel(const float* __restrict__ zin,
                                                  float* __restrict__ zsq) {
  const int n  = blockIdx.x * 256 + threadIdx.x;
  const int b  = n >> 12;
  const int hw = n & 4095;
  const float* p = zin + (size_t)b * DIM * HW + hw;   // element d at p[d*HW]
  float h0 = pairwise_sq_128(p, HW);
  float h1 = pairwise_sq_128(p + (size_t)128 * HW, HW);
  zsq[n] = h0 + h1;
}

// ---------------- kernel B: esq_k = fl32 sum(e_k^2), same tree ----------------
__global__ void esq_kernel(const float* __restrict__ emb, float* __restrict__ esq) {
  const int k = blockIdx.x * 256 + threadIdx.x;
  if (k >= KCODES) return;
  const float* p = emb + (size_t)k * DIM;
  float h0 = pairwise_sq_128(p, 1);
  float h1 = pairwise_sq_128(p + 128, 1);
  esq[k] = h0 + h1;
}

// ---------------- kernel C: fp32 scores (replicating reference rounding) + argmin ----------------
// dist32 = fl( fl(Z - 2*mm) + esq ), mm = sequential fp32 fma chain over d=0..255
// (single accumulator, ascending d — matches CPU sgemm micro-kernel accumulation:
//  OpenBLAS/Eigen/BLIS all keep one accumulator per C element, k innermost, fma).
__global__ __launch_bounds__(256) void score_kernel(
    const float* __restrict__ zin, const float* __restrict__ emb,
    const float* __restrict__ zsq, const float* __restrict__ esq,
    int* __restrict__ idx) {
  __shared__ SmemB sm;
  const int tid = threadIdx.x;
  const int tx = tid & 15;       // vector group: local vectors tx*8 .. tx*8+7
  const int ty = tid >> 4;       // code group:   codes ty*8 .. ty*8+7 within k-tile
  const int n0 = blockIdx.x * TN;
  const int b  = n0 >> 12;       // blocks never straddle a batch (128 | 4096)
  const int hw0 = n0 & 4095;
  const float* zbase = zin + (size_t)b * DIM * HW + hw0;

  float zr2[8];
  #pragma unroll
  for (int r = 0; r < 8; ++r) zr2[r] = zsq[n0 + tx * 8 + r];

  float m1[8]; int i1[8];
  #pragma unroll
  for (int r = 0; r < 8; ++r) { m1[r] = FLT_MAX; i1[r] = 0; }

  for (int kt = 0; kt < KCODES / TK; ++kt) {
    const int k0 = kt * TK;
    float acc[8][8];
    #pragma unroll
    for (int r = 0; r < 8; ++r)
      #pragma unroll
      for (int u = 0; u < 8; ++u) acc[r][u] = 0.f;

    float esqr[8];
    #pragma unroll
    for (int u = 0; u < 8; ++u) esqr[u] = esq[k0 + ty * 8 + u];

    for (int dc = 0; dc < DIM / DC; ++dc) {
      // stage z chunk [DC][TN] — coalesced (rows contiguous in global)
      #pragma unroll
      for (int i = 0; i < 4; ++i) {
        int f = i * 256 + tid;            // 0..1023 float4s
        int d  = f >> 5;                  // 0..31
        int c4 = f & 31;                  // float4 column
        float4 v = *reinterpret_cast<const float4*>(zbase + (size_t)(dc * DC + d) * HW + c4 * 4);
        *reinterpret_cast<float4*>(&sm.s.z[d][c4 * 4]) = v;
      }
      // stage e chunk transposed e[d][code]
      #pragma unroll
      for (int i = 0; i < 4; ++i) {
        int f = i * 256 + tid;
        int r = f & 127;                  // code within tile
        int q = f >> 7;                   // 0..7 -> d-positions q*4..q*4+3
        float4 v = *reinterpret_cast<const float4*>(emb + (size_t)(k0 + r) * DIM + dc * DC + q * 4);
        sm.s.e[q * 4 + 0][r] = v.x;
        sm.s.e[q * 4 + 1][r] = v.y;
        sm.s.e[q * 4 + 2][r] = v.z;
        sm.s.e[q * 4 + 3][r] = v.w;
      }
      __syncthreads();
      // sequential-d fma accumulation (order d = dc*32 .. dc*32+31 — globally ascending)
      #pragma unroll 4
      for (int d = 0; d < DC; ++d) {
        float zr[8], er[8];
        reinterpret_cast<float4&>(zr[0]) = reinterpret_cast<const float4&>(sm.s.z[d][tx * 8]);
        reinterpret_cast<float4&>(zr[4]) = reinterpret_cast<const float4&>(sm.s.z[d][tx * 8 + 4]);
        reinterpret_cast<float4&>(er[0]) = reinterpret_cast<const float4&>(sm.s.e[d][ty * 8]);
        reinterpret_cast<float4&>(er[4]) = reinterpret_cast<const float4&>(sm.s.e[d][ty * 8 + 4]);
        #pragma unroll
        for (int r = 0; r < 8; ++r)
          #pragma unroll
          for (int u = 0; u < 8; ++u)
            acc[r][u] = fmaf(zr[r], er[u], acc[r][u]);
      }
      __syncthreads();
    }
    // fold: replicate reference rounding chain, ascending k per thread (first-min kept)
    #pragma unroll
    for (int u = 0; u < 8; ++u) {
      const int k = k0 + ty * 8 + u;
      #pragma unroll
      for (int r = 0; r < 8; ++r) {
        float t = zr2[r] - 2.0f * acc[r][u];   // fl(Z - 2mm): one rounding (2*acc exact)
        float s = t + esqr[u];                 // fl(t + esq): second rounding
        if (s < m1[r]) { m1[r] = s; i1[r] = k; }
      }
    }
  }

  // cross-thread (ty) argmin merge; exact-tie -> smallest index (numpy first-occurrence)
  #pragma unroll
  for (int r = 0; r < 8; ++r) {
    sm.m.m1[ty][tx * 8 + r] = m1[r];
    sm.m.i1[ty][tx * 8 + r] = i1[r];
  }
  __syncthreads();
  if (tid < TN) {
    const int v = tid;
    float bm = FLT_MAX; int bi = 0x7fffffff;
    for (int t = 0; t < 16; ++t) {
      float a = sm.m.m1[t][v];
      int   ai = sm.m.i1[t][v];
      if (a < bm || (a == bm && ai < bi)) { bm = a; bi = ai; }
    }
    idx[n0 + v] = bi;
  }
}

// ---------------- kernel D: gather + write z_q and quantized (BCHW) ----------------
__global__ __launch_bounds__(256) void output_kernel(
    const float* __restrict__ zin, const float* __restrict__ emb,
    const int* __restrict__ idx, float* __restrict__ out) {
  const int n  = blockIdx.x * 256 + threadIdx.x;   // vector id
  const int c0 = blockIdx.y * 32;
  const int b  = n >> 12;
  const int hw = n & 4095;
  const int id = idx[n];
  const float* er = emb + (size_t)id * DIM;
  float* zq = out;
  float* qu = out + (size_t)OUTHALF;
  const size_t base = (size_t)b * DIM * HW + hw;
  #pragma unroll 4
  for (int c = c0; c < c0 + 32; ++c) {
    float q = er[c];
    size_t off = base + (size_t)c * HW;
    float z = zin[off];
    zq[off] = z + (q - z);   // fl(z + fl(q-z)) — matches reference STE bit-for-bit
    qu[off] = q;
  }
}

extern "C" void kernel_launch(void* const* d_in, const int* in_sizes, int n_in,
                              void* d_out, int out_size, void* d_ws, size_t ws_size,
                              hipStream_t stream) {
  const float* zin = (const float*)d_in[0];
  const float* emb = (const float*)d_in[1];
  float* out = (float*)d_out;

  char* ws = (char*)d_ws;
  int*   idx = (int*)ws;                           // 65536 ints
  float* zsq = (float*)(ws + (size_t)NVEC * 4);    // 65536 floats
  float* esq = (float*)(ws + (size_t)NVEC * 8);    // 1024 floats

  zsq_kernel<<<NVEC / 256, 256, 0, stream>>>(zin, zsq);
  esq_kernel<<<KCODES / 256, 256, 0, stream>>>(emb, esq);
  score_kernel<<<NVEC / TN, 256, 0, stream>>>(zin, emb, zsq, esq, idx);
  output_kernel<<<dim3(NVEC / 256, DIM / 32), 256, 0, stream>>>(zin, emb, idx, out);
}

// Round 7
// 676.629 us; speedup vs baseline: 1.0949x; 1.0949x over previous
//
#include <hip/hip_runtime.h>
#include <cfloat>

// VectorQuantizer: z_in [16,256,64,64] fp32, emb [1024,256] fp32
#define HW      4096
#define DIM     256
#define KCODES  1024
#define NVEC    65536
#define OUTHALF 16777216

// score-kernel tiling
#define TN     128   // vectors per block
#define TK     128   // codes per k-tile
#define DC     32    // d-chunk staged in LDS
#define ESTR   132   // padded e-tile row stride
#define KSPLIT 2     // split-K factor (codes per block = KCODES/KSPLIT = 512)

// forces x to be materialized (rounded) — prevents mul+add fma contraction
#define FBAR(x) asm volatile("" : "+v"(x))

struct StageMem {
  float z[DC][TN];    // 16 KB — rows are slot-permuted (see stage/read)
  float e[DC][ESTR];  // 16.5 KB, e[d][code]
};
struct MergeMem {
  float m1[16][TN];
  int   i1[16][TN];
};
union __align__(16) SmemB {
  StageMem s;
  MergeMem m;
};

// numpy pairwise_sum replication for sum of 128 squares (stride in elements):
// r[0..7] accumulate stride-8, combine ((r0+r1)+(r2+r3)) + ((r4+r5)+(r6+r7)).
// Squares individually rounded (numpy materializes x**2 first) — FBAR blocks fma.
__device__ __forceinline__ float pairwise_sq_128(const float* __restrict__ p, long stride) {
  float r[8];
  #pragma unroll
  for (int j = 0; j < 8; ++j) {
    float v = p[(size_t)j * stride];
    float s = v * v; FBAR(s);
    r[j] = s;
  }
  for (int i = 8; i < 128; i += 8) {
    #pragma unroll
    for (int j = 0; j < 8; ++j) {
      float v = p[(size_t)(i + j) * stride];
      float s = v * v; FBAR(s);
      r[j] += s;
    }
  }
  return ((r[0] + r[1]) + (r[2] + r[3])) + ((r[4] + r[5]) + (r[6] + r[7]));
}

// ---------------- kernel A: Z_n = fl32 sum(z_n^2), numpy tree; 2 threads/vector ----------------
__global__ __launch_bounds__(256) void zsq_kernel(const float* __restrict__ zin,
                                                  float* __restrict__ zsq) {
  __shared__ float ph[2][128];
  const int v = threadIdx.x & 127;
  const int h = threadIdx.x >> 7;           // half 0: d 0..127, half 1: d 128..255
  const int n  = blockIdx.x * 128 + v;
  const int b  = n >> 12;
  const int hw = n & 4095;
  const float* p = zin + (size_t)b * DIM * HW + hw + (size_t)h * 128 * HW;
  ph[h][v] = pairwise_sq_128(p, HW);
  __syncthreads();
  if (threadIdx.x < 128)
    zsq[blockIdx.x * 128 + threadIdx.x] = ph[0][threadIdx.x] + ph[1][threadIdx.x]; // h0+h1 order
}

// ---------------- kernel B: esq_k = fl32 sum(e_k^2), same tree ----------------
__global__ void esq_kernel(const float* __restrict__ emb, float* __restrict__ esq) {
  const int k = blockIdx.x * 256 + threadIdx.x;
  if (k >= KCODES) return;
  const float* p = emb + (size_t)k * DIM;
  float h0 = pairwise_sq_128(p, 1);
  float h1 = pairwise_sq_128(p + 128, 1);
  esq[k] = h0 + h1;
}

// ---------------- kernel C: fp32 scores + per-split argmin partials ----------------
// dist32 = fl( fl(Z - 2*mm) + esq ), mm = sequential fp32 fma chain over d=0..255.
// Block bid: ks = bid&1 (k half), vblk = bid>>1 (adjacent pair shares z-tile -> L2 reuse).
__global__ __launch_bounds__(256) void score_kernel(
    const float* __restrict__ zin, const float* __restrict__ emb,
    const float* __restrict__ zsq, const float* __restrict__ esq,
    float* __restrict__ pm1, int* __restrict__ pi1) {
  __shared__ SmemB sm;
  const int tid = threadIdx.x;
  const int tx = tid & 15;       // vector group: local vectors tx*8 .. tx*8+7
  const int ty = tid >> 4;       // code group:   codes ty*8 .. ty*8+7 within k-tile
  const int ks   = blockIdx.x & (KSPLIT - 1);
  const int vblk = blockIdx.x >> 1;          // log2(KSPLIT)=1
  const int n0 = vblk * TN;
  const int b  = n0 >> 12;       // blocks never straddle a batch (128 | 4096)
  const int hw0 = n0 & 4095;
  const float* zbase = zin + (size_t)b * DIM * HW + hw0;

  float zr2[8];
  #pragma unroll
  for (int r = 0; r < 8; ++r) zr2[r] = zsq[n0 + tx * 8 + r];

  float m1[8]; int i1[8];
  #pragma unroll
  for (int r = 0; r < 8; ++r) { m1[r] = FLT_MAX; i1[r] = 0; }

  for (int kt = 0; kt < (KCODES / KSPLIT) / TK; ++kt) {
    const int k0 = ks * (KCODES / KSPLIT) + kt * TK;
    float acc[8][8];
    #pragma unroll
    for (int r = 0; r < 8; ++r)
      #pragma unroll
      for (int u = 0; u < 8; ++u) acc[r][u] = 0.f;

    float esqr[8];
    #pragma unroll
    for (int u = 0; u < 8; ++u) esqr[u] = esq[k0 + ty * 8 + u];

    for (int dc = 0; dc < DIM / DC; ++dc) {
      // stage z chunk [DC][TN], slot-permuted rows: float4 of columns c4*4..c4*4+3
      // goes to slot s = (c4&1)*16 + (c4>>1)  ->  reads at 16*tx B are 2-way (free)
      #pragma unroll
      for (int i = 0; i < 4; ++i) {
        int f = i * 256 + tid;            // 0..1023 float4s
        int d  = f >> 5;                  // 0..31
        int c4 = f & 31;                  // source float4 column
        int s  = ((c4 & 1) << 4) | (c4 >> 1);
        float4 v = *reinterpret_cast<const float4*>(zbase + (size_t)(dc * DC + d) * HW + c4 * 4);
        *reinterpret_cast<float4*>(&sm.s.z[d][s * 4]) = v;
      }
      // stage e chunk transposed e[d][code]
      #pragma unroll
      for (int i = 0; i < 4; ++i) {
        int f = i * 256 + tid;
        int r = f & 127;                  // code within tile
        int q = f >> 7;                   // 0..7 -> d-positions q*4..q*4+3
        float4 v = *reinterpret_cast<const float4*>(emb + (size_t)(k0 + r) * DIM + dc * DC + q * 4);
        sm.s.e[q * 4 + 0][r] = v.x;
        sm.s.e[q * 4 + 1][r] = v.y;
        sm.s.e[q * 4 + 2][r] = v.z;
        sm.s.e[q * 4 + 3][r] = v.w;
      }
      __syncthreads();
      // sequential-d fma accumulation (globally ascending d)
      #pragma unroll 4
      for (int d = 0; d < DC; ++d) {
        float zr[8], er[8];
        // slot tx -> floats tx*8..+3 ; slot 16+tx -> floats tx*8+4..+7
        reinterpret_cast<float4&>(zr[0]) = reinterpret_cast<const float4&>(sm.s.z[d][tx * 4]);
        reinterpret_cast<float4&>(zr[4]) = reinterpret_cast<const float4&>(sm.s.z[d][64 + tx * 4]);
        reinterpret_cast<float4&>(er[0]) = reinterpret_cast<const float4&>(sm.s.e[d][ty * 8]);
        reinterpret_cast<float4&>(er[4]) = reinterpret_cast<const float4&>(sm.s.e[d][ty * 8 + 4]);
        #pragma unroll
        for (int r = 0; r < 8; ++r)
          #pragma unroll
          for (int u = 0; u < 8; ++u)
            acc[r][u] = fmaf(zr[r], er[u], acc[r][u]);
      }
      __syncthreads();
    }
    // fold: replicate reference rounding chain, ascending k per thread
    #pragma unroll
    for (int u = 0; u < 8; ++u) {
      const int k = k0 + ty * 8 + u;
      #pragma unroll
      for (int r = 0; r < 8; ++r) {
        float t = zr2[r] - 2.0f * acc[r][u];   // fl(Z - 2mm)
        float s = t + esqr[u];                 // fl(t + esq)
        if (s < m1[r]) { m1[r] = s; i1[r] = k; }
      }
    }
  }

  // cross-thread (ty) argmin merge; exact-tie -> smallest index
  #pragma unroll
  for (int r = 0; r < 8; ++r) {
    sm.m.m1[ty][tx * 8 + r] = m1[r];
    sm.m.i1[ty][tx * 8 + r] = i1[r];
  }
  __syncthreads();
  if (tid < TN) {
    const int v = tid;
    float bm = FLT_MAX; int bi = 0x7fffffff;
    for (int t = 0; t < 16; ++t) {
      float a = sm.m.m1[t][v];
      int   ai = sm.m.i1[t][v];
      if (a < bm || (a == bm && ai < bi)) { bm = a; bi = ai; }
    }
    pm1[(size_t)ks * NVEC + n0 + v] = bm;
    pi1[(size_t)ks * NVEC + n0 + v] = bi;
  }
}

// ---------------- kernel C2: merge split-K partials (split 0 wins ties: lower k) ----------------
__global__ __launch_bounds__(256) void merge_kernel(const float* __restrict__ pm1,
                                                    const int* __restrict__ pi1,
                                                    int* __restrict__ idx) {
  const int v = blockIdx.x * 256 + threadIdx.x;
  float d0 = pm1[v];
  float d1 = pm1[NVEC + v];
  int   i0 = pi1[v];
  int   i1 = pi1[NVEC + v];
  idx[v] = (d1 < d0) ? i1 : i0;   // strict <: equal dist -> split 0 (smaller k)
}

// ---------------- kernel D: gather + write z_q and quantized (BCHW), float4 over hw ----------------
__global__ __launch_bounds__(256) void output_kernel(
    const float* __restrict__ zin, const float* __restrict__ emb,
    const int* __restrict__ idx, float* __restrict__ out) {
  const int t   = blockIdx.x * 256 + threadIdx.x;  // hw-quad id 0..16383
  const int b   = t >> 10;                         // 1024 quads per batch
  const int hw0 = (t & 1023) * 4;
  const int c0  = blockIdx.y * 8;
  const int4 ids = *reinterpret_cast<const int4*>(&idx[(b << 12) + hw0]);
  const float* e0 = emb + (size_t)ids.x * DIM;
  const float* e1 = emb + (size_t)ids.y * DIM;
  const float* e2 = emb + (size_t)ids.z * DIM;
  const float* e3 = emb + (size_t)ids.w * DIM;
  float* zq = out;
  float* qu = out + (size_t)OUTHALF;
  const size_t base = (size_t)b * DIM * HW + hw0;
  #pragma unroll
  for (int c = c0; c < c0 + 8; ++c) {
    const size_t off = base + (size_t)c * HW;
    float4 z4 = *reinterpret_cast<const float4*>(zin + off);
    float4 q4 = make_float4(e0[c], e1[c], e2[c], e3[c]);
    float4 o4;
    o4.x = z4.x + (q4.x - z4.x);   // fl(z + fl(q-z)) — matches reference STE
    o4.y = z4.y + (q4.y - z4.y);
    o4.z = z4.z + (q4.z - z4.z);
    o4.w = z4.w + (q4.w - z4.w);
    *reinterpret_cast<float4*>(zq + off) = o4;
    *reinterpret_cast<float4*>(qu + off) = q4;
  }
}

extern "C" void kernel_launch(void* const* d_in, const int* in_sizes, int n_in,
                              void* d_out, int out_size, void* d_ws, size_t ws_size,
                              hipStream_t stream) {
  const float* zin = (const float*)d_in[0];
  const float* emb = (const float*)d_in[1];
  float* out = (float*)d_out;

  char* ws = (char*)d_ws;
  float* pm1 = (float*)ws;                                   // [2][NVEC] = 512 KB
  int*   pi1 = (int*)(ws + (size_t)KSPLIT * NVEC * 4);       // [2][NVEC] = 512 KB
  int*   idx = (int*)(ws + (size_t)2 * KSPLIT * NVEC * 4);   // [NVEC]    = 256 KB
  float* zsq = (float*)(ws + (size_t)(2 * KSPLIT + 1) * NVEC * 4); // [NVEC] = 256 KB
  float* esq = (float*)(ws + (size_t)(2 * KSPLIT + 2) * NVEC * 4); // [KCODES] = 4 KB

  zsq_kernel<<<NVEC / 128, 256, 0, stream>>>(zin, zsq);
  esq_kernel<<<KCODES / 256, 256, 0, stream>>>(emb, esq);
  score_kernel<<<(NVEC / TN) * KSPLIT, 256, 0, stream>>>(zin, emb, zsq, esq, pm1, pi1);
  merge_kernel<<<NVEC / 256, 256, 0, stream>>>(pm1, pi1, idx);
  output_kernel<<<dim3(NVEC / 1024, DIM / 8), 256, 0, stream>>>(zin, emb, idx, out);
}